// Round 1
// 282.795 us; speedup vs baseline: 1.0279x; 1.0279x over previous
//
#include <hip/hip_runtime.h>
#include <cstdint>
#include <cstddef>

// Problem constants (fixed by setup_inputs)
#define N_B 32
#define D_MODEL 256
#define H_N 8
#define HD 32
#define GP 1024   // grouped protein length
#define GS 256    // grouped sm length
#define LOG2E 1.4426950408889634f

typedef __attribute__((ext_vector_type(8))) short short8;   // 8 bf16 = 4 VGPRs
typedef __attribute__((ext_vector_type(4))) float floatx4;

#if __has_builtin(__builtin_amdgcn_exp2f)
#define EXP2(x) __builtin_amdgcn_exp2f(x)
#else
#define EXP2(x) exp2f(x)
#endif

__device__ __forceinline__ unsigned short f2bf(float f) {
    unsigned u = __float_as_uint(f);
    u = (u + 0x7FFFu + ((u >> 16) & 1u)) >> 16;   // RNE
    return (unsigned short)u;
}

// pack two floats -> bf16x2 (lo = a, hi = b); fast round (attn P path only)
__device__ __forceinline__ unsigned pack_bf16(float a, float b) {
    unsigned ua = __float_as_uint(a) + 0x8000u;
    unsigned ub = __float_as_uint(b) + 0x8000u;
    return __builtin_amdgcn_perm(ub, ua, 0x07060302);  // [b.hi16][a.hi16]
}

// exact-RNE pack (matches old f2bf path numerics for V)
__device__ __forceinline__ unsigned pack_bf16_rne(float a, float b) {
    return (unsigned)f2bf(a) | ((unsigned)f2bf(b) << 16);
}

// ---------------------------------------------------------------------------
// Fused prologue: both group-means (fp32 -> bf16) + both mask biases
// + (tail blocks) all 5 weight transposes.  One launch total.
#define PRO_A (N_B * GP * 64)
#define PRO_B (N_B * GS * 64)
#define PRO_C (N_B * GP)
#define PRO_D (N_B * GS)
#define PRO_BLOCKS ((PRO_A + PRO_B + PRO_C + PRO_D) / 256)   // 10400
#define WT_BLOCKS 80
__global__ __launch_bounds__(256) void prologue_w(
        const float4* __restrict__ prot, const float4* __restrict__ smx,
        const int* __restrict__ mp, const int* __restrict__ ms,
        ushort4* __restrict__ prot_g, ushort4* __restrict__ sm_g,
        float* __restrict__ bias_p, float* __restrict__ bias_s,
        const float* __restrict__ Wk_p, const float* __restrict__ Wv_p,
        const float* __restrict__ Wq_d, const float* __restrict__ Wk_d,
        const float* __restrict__ Wv_d,
        unsigned short* __restrict__ WTbig, unsigned short* __restrict__ WTsml) {
    __shared__ unsigned short sT[64 * 65];
    int blk = blockIdx.x;
    int t = threadIdx.x;
    if (blk < PRO_BLOCKS) {
        int gid = blk * 256 + t;
        if (gid < PRO_A + PRO_B) {
            const float4* x; ushort4* xg; int g2;
            if (gid < PRO_A) { x = prot; xg = prot_g; g2 = gid; }
            else { x = smx; xg = sm_g; g2 = gid - PRO_A; }
            int row = g2 >> 6, c = g2 & 63;
            const float4* p = x + (size_t)row * 256 + c;
            float4 a = p[0], b = p[64], cc = p[128], d = p[192];
            ushort4 r;
            r.x = f2bf(0.25f * (a.x + b.x + cc.x + d.x));
            r.y = f2bf(0.25f * (a.y + b.y + cc.y + d.y));
            r.z = f2bf(0.25f * (a.z + b.z + cc.z + d.z));
            r.w = f2bf(0.25f * (a.w + b.w + cc.w + d.w));
            xg[g2] = r;
        } else {
            int g2 = gid - (PRO_A + PRO_B);
            const int* m; float* bias;
            if (g2 < PRO_C) { m = mp; bias = bias_p; }
            else { m = ms; bias = bias_s; g2 -= PRO_C; }
            const int* p = m + (size_t)g2 * 4;
            bias[g2] = (p[0] | p[1] | p[2] | p[3]) ? 0.0f : -1442695.0f;
        }
    } else {
        // weight transpose: W [K=256][N=256] fp32 -> WT[p*256+col][k] bf16
        int wb = blk - PRO_BLOCKS;       // 0..79
        int y = wb >> 4, bx = wb & 15;
        const float* W; unsigned short* WT; int pidx;
        if (y < 2) { W = (y == 0) ? Wk_p : Wv_p; WT = WTbig; pidx = y; }
        else {
            int q = y - 2;
            W = (q == 0) ? Wq_d : (q == 1 ? Wk_d : Wv_d);
            WT = WTsml; pidx = q;
        }
        int kt = bx >> 2, ct = bx & 3;
        int k0 = kt * 64, c0 = ct * 64;
#pragma unroll
        for (int j = 0; j < 4; j++) {
            int idx = j * 256 + t;
            int kr = idx >> 4, cf = idx & 15;
            float4 v = *(const float4*)&W[(size_t)(k0 + kr) * 256 + c0 + cf * 4];
            sT[(cf * 4 + 0) * 65 + kr] = f2bf(v.x);
            sT[(cf * 4 + 1) * 65 + kr] = f2bf(v.y);
            sT[(cf * 4 + 2) * 65 + kr] = f2bf(v.z);
            sT[(cf * 4 + 3) * 65 + kr] = f2bf(v.w);
        }
        __syncthreads();
#pragma unroll
        for (int j = 0; j < 8; j++) {
            int idx = j * 256 + t;
            int cw = idx >> 5, kq = idx & 31;
            unsigned lo = sT[cw * 65 + kq * 2];
            unsigned hi = sT[cw * 65 + kq * 2 + 1];
            ((unsigned*)WT)[((size_t)pidx * 256 + c0 + cw) * 128 + (k0 >> 1) + kq] =
                lo | (hi << 16);
        }
    }
}

// ---------------------------------------------------------------------------
// Unified bf16 MFMA GEMM (both parts, one launch), XCD-swizzled block ids.
// K/Q tiles: direct head-major bf16 store (as before).
// V tiles: fused transpose epilogue -> writes Vt[(nb*8+h)*32+d][Gk] directly
// with the per-32-key column permutation pos32 = 2*(k&15) + (k>>4), i.e. the
// old vtrans output, eliminating that kernel + 42 MB of traffic.
__global__ __launch_bounds__(256) void gemm_bf16(
        const unsigned short* __restrict__ Abig,
        const unsigned short* __restrict__ WTbig,
        const unsigned short* __restrict__ Asml,
        const unsigned short* __restrict__ WTsml,
        unsigned short* __restrict__ Kp, unsigned short* __restrict__ Vpt,
        unsigned short* __restrict__ Qd, unsigned short* __restrict__ Ksd,
        unsigned short* __restrict__ Vsdt) {
    __shared__ alignas(16) unsigned short lds[128 * 128];   // 32 KB
    unsigned short* As = lds;           // [128][64] k-slab of A
    unsigned short* Bs = lds + 8192;    // [128][64] k-slab of B

    // bijective XCD swizzle: 1408 % 8 == 0 -> 176 consecutive tiles per XCD
    int bid = blockIdx.x;
    int id = (bid & 7) * 176 + (bid >> 3);

    const unsigned short *A, *WT;
    unsigned short *oK0, *oK1, *oV;
    int Gg, lgG, row0, col0;
    float scale0;
    bool isV;
    if (id < 1024) {
        A = Abig; WT = WTbig; oK0 = Kp; oK1 = Kp; oV = Vpt;
        Gg = GP; lgG = 10; scale0 = 1.0f;
        col0 = (id & 3) << 7; row0 = (id >> 2) << 7;
        isV = (col0 >= 256);
    } else {
        int tq = id - 1024;
        A = Asml; WT = WTsml; oK0 = Qd; oK1 = Ksd; oV = Vsdt;
        Gg = GS; lgG = 8; scale0 = LOG2E;
        col0 = (tq % 6) << 7; row0 = (tq / 6) << 7;
        isV = (col0 >= 512);
    }
    const int tid = threadIdx.x;
    const int ln = tid & 63, wave = tid >> 6;
    const int m16 = ln & 15, quad = ln >> 4;
    const int wm = (wave & 1) * 64, wn = (wave >> 1) * 64;

    // staging lane constants: slab j covers units (j*4+wave)*64 + ln
    const uint4* gA[4];
    const uint4* gB[4];
    unsigned ldsoff[4];
#pragma unroll
    for (int j = 0; j < 4; j++) {
        int u = (j * 4 + wave) * 64 + ln;
        int r = u >> 3, s = u & 7;
        int sg = (s - r) & 7;
        gA[j] = (const uint4*)A + (size_t)(row0 + r) * 32 + sg;
        gB[j] = (const uint4*)WT + (size_t)(col0 + r) * 32 + sg;
        ldsoff[j] = (unsigned)((j * 4 + wave) * 512);   // shorts
    }
    // frag read byte-addresses (k0-invariant; kh toggles bit 6)
    int aaddr[4], baddr[4];
#pragma unroll
    for (int i = 0; i < 4; i++) {
        int rA = wm + i * 16 + m16;
        aaddr[i] = rA * 128 + ((quad + rA) & 7) * 16;
        int rB = wn + i * 16 + m16;
        baddr[i] = rB * 128 + ((quad + rB) & 7) * 16;
    }

    floatx4 acc[4][4] = {};
    for (int ko = 0; ko < 32; ko += 8) {     // k in uint4 units (256/8)
        __syncthreads();
#pragma unroll
        for (int j = 0; j < 4; j++) {
            __builtin_amdgcn_global_load_lds(
                (const __attribute__((address_space(1))) void*)(gA[j] + ko),
                (__attribute__((address_space(3))) void*)&As[ldsoff[j]], 16, 0, 0);
            __builtin_amdgcn_global_load_lds(
                (const __attribute__((address_space(1))) void*)(gB[j] + ko),
                (__attribute__((address_space(3))) void*)&Bs[ldsoff[j]], 16, 0, 0);
        }
        __syncthreads();
#pragma unroll
        for (int kh = 0; kh < 2; kh++) {
            short8 af[4], bfr[4];
#pragma unroll
            for (int i = 0; i < 4; i++) {
                af[i]  = *(const short8*)((const char*)As + (aaddr[i] ^ (kh << 6)));
                bfr[i] = *(const short8*)((const char*)Bs + (baddr[i] ^ (kh << 6)));
            }
#pragma unroll
            for (int im = 0; im < 4; im++)
#pragma unroll
                for (int in = 0; in < 4; in++)
                    acc[im][in] = __builtin_amdgcn_mfma_f32_16x16x32_bf16(
                        af[im], bfr[in], acc[im][in], 0, 0, 0);
        }
    }

    if (!isV) {
        // direct epilogue: C layout col=lane&15, row=quad*4+reg
#pragma unroll
        for (int im = 0; im < 4; im++) {
#pragma unroll
            for (int in = 0; in < 4; in++) {
                int colg = col0 + wn + in * 16 + m16;
                int p = colg >> 8, h = (colg >> 5) & 7, d = colg & 31;
                unsigned short* ob = (p == 0) ? oK0 : oK1;
                float sc = (p == 0) ? scale0 : 1.0f;
#pragma unroll
                for (int r = 0; r < 4; r++) {
                    int Mrow = row0 + wm + im * 16 + quad * 4 + r;
                    int nb = Mrow >> lgG, g = Mrow & (Gg - 1);
                    ob[(((size_t)nb * 8 + h) * Gg + g) * 32 + d] =
                        f2bf(acc[im][in][r] * sc);
                }
            }
        }
    } else {
        // fused V-transpose epilogue (replaces vtrans kernel).
        // key k = wm + im*16 + quad*4 + r (local row, 0..127);
        // permpos(k) = (k>>5)*32 + 8*quad + 2*r + (im&1)  [vtrans's mapping]
        // LDS tile T[col][pos], XOR-swizzled in the 8-short-group bits.
        __syncthreads();   // all waves done reading As/Bs frags
#pragma unroll
        for (int in = 0; in < 4; in++) {
            int col = wn + in * 16 + m16;                 // 0..127
            unsigned cb = (unsigned)col * 128;
            unsigned swz = (unsigned)((col & 15) << 3);
#pragma unroll
            for (int imp = 0; imp < 2; imp++) {
#pragma unroll
                for (int r = 0; r < 4; r++) {
                    unsigned pos = (unsigned)(wm + imp * 32 + 8 * quad + 2 * r);
                    *(unsigned*)&lds[cb + (pos ^ swz)] =
                        pack_bf16_rne(acc[2 * imp][in][r], acc[2 * imp + 1][in][r]);
                }
            }
        }
        __syncthreads();
        int nb = row0 >> lgG;
        int kbase = row0 & (Gg - 1);
        const int tcol = tid >> 4, p8 = tid & 15;
#pragma unroll
        for (int j = 0; j < 8; j++) {
            int col = j * 16 + tcol;
            int colg = col0 + col;
            int h = (colg >> 5) & 7, d = colg & 31;
            uint4 v = *(const uint4*)&lds[col * 128 + ((p8 * 8) ^ ((col & 15) << 3))];
            *(uint4*)(oV + (((size_t)nb * 8 + h) * 32 + d) * Gg + kbase + p8 * 8) = v;
        }
    }
}

// ---------------------------------------------------------------------------
// Barrier-free flash attention, 32 queries/wave (two 16-q tiles sharing K/V
// frags) + register double-buffered prefetch of next chunk's frags+biases.
struct KVFrag { uint4 k0, k1, v0, v1; float b0, b1; };

__device__ __forceinline__ KVFrag load_frag(
        const uint4* K4, const uint4* V4, const float* bias,
        int c, int Gk8, int m16, int quad) {
    KVFrag f;
    f.k0 = K4[(c * 32 + m16) * 4 + quad];
    f.k1 = K4[(c * 32 + 16 + m16) * 4 + quad];
    f.v0 = V4[(size_t)m16 * Gk8 + c * 4 + quad];
    f.v1 = V4[(size_t)(16 + m16) * Gk8 + c * 4 + quad];
    f.b0 = bias[c * 32 + m16];
    f.b1 = bias[c * 32 + 16 + m16];
    return f;
}

__device__ __forceinline__ void attn_stream(
        const unsigned short* __restrict__ Kb,
        const unsigned short* __restrict__ Vtb,
        const float* __restrict__ bias, int Lk,
        short8 qfA, short8 qfB, unsigned* sPw,
        int m16, int quad, float* lA, float* lB,
        floatx4& oA0, floatx4& oA1, floatx4& oB0, floatx4& oB1) {
    const uint4* K4 = (const uint4*)Kb;
    const uint4* V4 = (const uint4*)Vtb;
    const int Gk8 = Lk >> 3;
    const int nchunks = Lk >> 5;
    KVFrag cur = load_frag(K4, V4, bias, 0, Gk8, m16, quad);
    for (int c = 0; c < nchunks; c++) {
        int cn = (c + 1 < nchunks) ? c + 1 : c;
        KVFrag nxt = load_frag(K4, V4, bias, cn, Gk8, m16, quad);
        union { uint4 u; short8 v; } t0, t1, pA, pB;
        t0.u = cur.k0; t1.u = cur.k1;
        floatx4 z = {0.f, 0.f, 0.f, 0.f};
        __builtin_amdgcn_s_setprio(1);
        floatx4 sA0 = __builtin_amdgcn_mfma_f32_16x16x32_bf16(qfA, t0.v, z, 0, 0, 0);
        floatx4 sA1 = __builtin_amdgcn_mfma_f32_16x16x32_bf16(qfA, t1.v, z, 0, 0, 0);
        floatx4 sB0 = __builtin_amdgcn_mfma_f32_16x16x32_bf16(qfB, t0.v, z, 0, 0, 0);
        floatx4 sB1 = __builtin_amdgcn_mfma_f32_16x16x32_bf16(qfB, t1.v, z, 0, 0, 0);
        __builtin_amdgcn_s_setprio(0);
#pragma unroll
        for (int r = 0; r < 4; r++) {            // row q = quad*4 + r
            float eA0 = EXP2(sA0[r] + cur.b0);
            float eA1 = EXP2(sA1[r] + cur.b1);
            float eB0 = EXP2(sB0[r] + cur.b0);
            float eB1 = EXP2(sB1[r] + cur.b1);
            lA[r] += eA0 + eA1;
            lB[r] += eB0 + eB1;
            sPw[(quad * 4 + r) * 20 + m16] = pack_bf16(eA0, eA1);
            sPw[320 + (quad * 4 + r) * 20 + m16] = pack_bf16(eB0, eB1);
        }
        pA.u = *(const uint4*)&sPw[m16 * 20 + quad * 4];
        pB.u = *(const uint4*)&sPw[320 + m16 * 20 + quad * 4];
        t0.u = cur.v0; t1.u = cur.v1;
        __builtin_amdgcn_s_setprio(1);
        oA0 = __builtin_amdgcn_mfma_f32_16x16x32_bf16(pA.v, t0.v, oA0, 0, 0, 0);
        oA1 = __builtin_amdgcn_mfma_f32_16x16x32_bf16(pA.v, t1.v, oA1, 0, 0, 0);
        oB0 = __builtin_amdgcn_mfma_f32_16x16x32_bf16(pB.v, t0.v, oB0, 0, 0, 0);
        oB1 = __builtin_amdgcn_mfma_f32_16x16x32_bf16(pB.v, t1.v, oB1, 0, 0, 0);
        __builtin_amdgcn_s_setprio(0);
        cur = nxt;
    }
}

__global__ __launch_bounds__(256) void attn_mfma(
        const unsigned short* __restrict__ Qd, const unsigned short* __restrict__ Kp,
        const unsigned short* __restrict__ Vpt, const unsigned short* __restrict__ Ksd,
        const unsigned short* __restrict__ Vsdt, const float* __restrict__ bias_p,
        const float* __restrict__ bias_s, float* __restrict__ out) {
    __shared__ alignas(16) unsigned sP[4][640];
    const int b = blockIdx.x;
    const int n = b >> 4, h = (b >> 1) & 7, qq = b & 1;
    const int tid = threadIdx.x, wave = tid >> 6, ln = tid & 63;
    const int m16 = ln & 15, quad = ln >> 4;
    const int q0 = qq * 128 + wave * 32;     // tile A: q0.., tile B: q0+16..
    unsigned* sPw = sP[wave];

    union { uint4 u; short8 v; } qfA, qfB;
    qfA.u = ((const uint4*)Qd)[(((size_t)n * 8 + h) * GS + q0 + m16) * 4 + quad];
    qfB.u = ((const uint4*)Qd)[(((size_t)n * 8 + h) * GS + q0 + 16 + m16) * 4 + quad];

    float lAdp[4] = {0, 0, 0, 0}, lBdp[4] = {0, 0, 0, 0};
    float lAdd[4] = {0, 0, 0, 0}, lBdd[4] = {0, 0, 0, 0};
    floatx4 oAdp0 = {}, oAdp1 = {}, oBdp0 = {}, oBdp1 = {};
    floatx4 oAdd0 = {}, oAdd1 = {}, oBdd0 = {}, oBdd1 = {};

    attn_stream(Kp + ((size_t)n * 8 + h) * GP * 32,
                Vpt + ((size_t)n * 8 + h) * GP * 32,
                bias_p + (size_t)n * GP, GP, qfA.v, qfB.v, sPw, m16, quad,
                lAdp, lBdp, oAdp0, oAdp1, oBdp0, oBdp1);
    attn_stream(Ksd + ((size_t)n * 8 + h) * GS * 32,
                Vsdt + ((size_t)n * 8 + h) * GS * 32,
                bias_s + (size_t)n * GS, GS, qfA.v, qfB.v, sPw, m16, quad,
                lAdd, lBdd, oAdd0, oAdd1, oBdd0, oBdd1);

#pragma unroll
    for (int r = 0; r < 4; r++) {
#pragma unroll
        for (int off = 1; off < 16; off <<= 1) {
            lAdp[r] += __shfl_xor(lAdp[r], off, 64);
            lBdp[r] += __shfl_xor(lBdp[r], off, 64);
            lAdd[r] += __shfl_xor(lAdd[r], off, 64);
            lBdd[r] += __shfl_xor(lBdd[r], off, 64);
        }
    }
#pragma unroll
    for (int r = 0; r < 4; r++) {
        // tile A
        int qrowA = q0 + quad * 4 + r;
        bool rmA = (bias_s[(size_t)n * GS + qrowA] == 0.0f);
        float idpA = 1.f / lAdp[r], iddA = 1.f / lAdd[r];
        float* obA = out + ((size_t)n * GS + qrowA) * 256 + h * 32;
        obA[m16]      = rmA ? 0.5f * (oAdp0[r] * idpA + oAdd0[r] * iddA) : 0.f;
        obA[16 + m16] = rmA ? 0.5f * (oAdp1[r] * idpA + oAdd1[r] * iddA) : 0.f;
        // tile B
        int qrowB = q0 + 16 + quad * 4 + r;
        bool rmB = (bias_s[(size_t)n * GS + qrowB] == 0.0f);
        float idpB = 1.f / lBdp[r], iddB = 1.f / lBdd[r];
        float* obB = out + ((size_t)n * GS + qrowB) * 256 + h * 32;
        obB[m16]      = rmB ? 0.5f * (oBdp0[r] * idpB + oBdd0[r] * iddB) : 0.f;
        obB[16 + m16] = rmB ? 0.5f * (oBdp1[r] * idpB + oBdd1[r] * iddB) : 0.f;
    }
}

// ---------------------------------------------------------------------------
extern "C" void kernel_launch(void* const* d_in, const int* in_sizes, int n_in,
                              void* d_out, int out_size, void* d_ws,
                              size_t ws_size, hipStream_t stream) {
    const float* protein   = (const float*)d_in[0];
    const float* smx       = (const float*)d_in[1];
    const int*   mask_prot = (const int*)d_in[2];
    const int*   mask_sm   = (const int*)d_in[3];
    const float* Wk_p = (const float*)d_in[4];
    const float* Wv_p = (const float*)d_in[5];
    const float* Wq_d = (const float*)d_in[6];
    const float* Wk_d = (const float*)d_in[7];
    const float* Wv_d = (const float*)d_in[8];
    float* out = (float*)d_out;

    char* ws = (char*)d_ws;
    unsigned short* prot_g = (unsigned short*)ws; ws += (size_t)N_B * GP * 256 * 2;
    unsigned short* sm_g   = (unsigned short*)ws; ws += (size_t)N_B * GS * 256 * 2;
    unsigned short* WTbig  = (unsigned short*)ws; ws += (size_t)512 * 256 * 2;
    unsigned short* WTsml  = (unsigned short*)ws; ws += (size_t)768 * 256 * 2;
    unsigned short* Kp     = (unsigned short*)ws; ws += (size_t)N_B * H_N * GP * 32 * 2;
    unsigned short* Vpt    = (unsigned short*)ws; ws += (size_t)N_B * H_N * GP * 32 * 2;
    unsigned short* Qd     = (unsigned short*)ws; ws += (size_t)N_B * H_N * GS * 32 * 2;
    unsigned short* Ksd    = (unsigned short*)ws; ws += (size_t)N_B * H_N * GS * 32 * 2;
    unsigned short* Vsdt   = (unsigned short*)ws; ws += (size_t)N_B * H_N * GS * 32 * 2;
    float* bias_p = (float*)ws; ws += (size_t)N_B * GP * 4;
    float* bias_s = (float*)ws; ws += (size_t)N_B * GS * 4;

    // 1. fused prologue: group means (bf16) + mask biases + weight transposes
    prologue_w<<<PRO_BLOCKS + WT_BLOCKS, 256, 0, stream>>>(
        (const float4*)protein, (const float4*)smx, mask_prot, mask_sm,
        (ushort4*)prot_g, (ushort4*)sm_g, bias_p, bias_s,
        Wk_p, Wv_p, Wq_d, Wk_d, Wv_d, WTbig, WTsml);

    // 2. unified MFMA projections -> head-major bf16 (Q pre-scaled by log2e),
    //    V written directly in transposed+permuted attention layout
    gemm_bf16<<<1024 + 384, 256, 0, stream>>>(
        prot_g, WTbig, sm_g, WTsml, Kp, Vpt, Qd, Ksd, Vsdt);

    // 3. barrier-free dual-stream flash-MFMA attention + merge
    attn_mfma<<<N_B * H_N * 2, 256, 0, stream>>>(Qd, Kp, Vpt, Ksd, Vsdt,
                                                 bias_p, bias_s, out);
}

// Round 3
// 277.882 us; speedup vs baseline: 1.0461x; 1.0177x over previous
//
#include <hip/hip_runtime.h>
#include <cstdint>
#include <cstddef>

// Problem constants (fixed by setup_inputs)
#define N_B 32
#define D_MODEL 256
#define H_N 8
#define HD 32
#define GP 1024   // grouped protein length
#define GS 256    // grouped sm length
#define LOG2E 1.4426950408889634f

typedef __attribute__((ext_vector_type(8))) short short8;   // 8 bf16 = 4 VGPRs
typedef __attribute__((ext_vector_type(4))) float floatx4;

#if __has_builtin(__builtin_amdgcn_exp2f)
#define EXP2(x) __builtin_amdgcn_exp2f(x)
#else
#define EXP2(x) exp2f(x)
#endif

__device__ __forceinline__ unsigned short f2bf(float f) {
    unsigned u = __float_as_uint(f);
    u = (u + 0x7FFFu + ((u >> 16) & 1u)) >> 16;   // RNE
    return (unsigned short)u;
}

// pack two floats -> bf16x2 (lo = a, hi = b); fast round (attn P path only)
__device__ __forceinline__ unsigned pack_bf16(float a, float b) {
    unsigned ua = __float_as_uint(a) + 0x8000u;
    unsigned ub = __float_as_uint(b) + 0x8000u;
    return __builtin_amdgcn_perm(ub, ua, 0x07060302);  // [b.hi16][a.hi16]
}

// exact-RNE pack (matches old f2bf path numerics for V)
__device__ __forceinline__ unsigned pack_bf16_rne(float a, float b) {
    return (unsigned)f2bf(a) | ((unsigned)f2bf(b) << 16);
}

// ---------------------------------------------------------------------------
// Fused prologue: (head blocks) all 5 weight transposes, then both
// group-means (fp32 -> bf16) + both mask biases.  wtrans first so the tiny
// transpose overlaps under the 168 MB mean stream instead of serializing
// as a tail.
#define PRO_A (N_B * GP * 64)
#define PRO_B (N_B * GS * 64)
#define PRO_C (N_B * GP)
#define PRO_D (N_B * GS)
#define PRO_BLOCKS ((PRO_A + PRO_B + PRO_C + PRO_D) / 256)   // 10400
#define WT_BLOCKS 80
__global__ __launch_bounds__(256) void prologue_w(
        const float4* __restrict__ prot, const float4* __restrict__ smx,
        const int* __restrict__ mp, const int* __restrict__ ms,
        ushort4* __restrict__ prot_g, ushort4* __restrict__ sm_g,
        float* __restrict__ bias_p, float* __restrict__ bias_s,
        const float* __restrict__ Wk_p, const float* __restrict__ Wv_p,
        const float* __restrict__ Wq_d, const float* __restrict__ Wk_d,
        const float* __restrict__ Wv_d,
        unsigned short* __restrict__ WTbig, unsigned short* __restrict__ WTsml) {
    __shared__ unsigned short sT[64 * 65];
    int blk = blockIdx.x;
    int t = threadIdx.x;
    if (blk >= WT_BLOCKS) {
        int gid = (blk - WT_BLOCKS) * 256 + t;
        if (gid < PRO_A + PRO_B) {
            const float4* x; ushort4* xg; int g2;
            if (gid < PRO_A) { x = prot; xg = prot_g; g2 = gid; }
            else { x = smx; xg = sm_g; g2 = gid - PRO_A; }
            int row = g2 >> 6, c = g2 & 63;
            const float4* p = x + (size_t)row * 256 + c;
            float4 a = p[0], b = p[64], cc = p[128], d = p[192];
            ushort4 r;
            r.x = f2bf(0.25f * (a.x + b.x + cc.x + d.x));
            r.y = f2bf(0.25f * (a.y + b.y + cc.y + d.y));
            r.z = f2bf(0.25f * (a.z + b.z + cc.z + d.z));
            r.w = f2bf(0.25f * (a.w + b.w + cc.w + d.w));
            xg[g2] = r;
        } else {
            int g2 = gid - (PRO_A + PRO_B);
            const int* m; float* bias;
            if (g2 < PRO_C) { m = mp; bias = bias_p; }
            else { m = ms; bias = bias_s; g2 -= PRO_C; }
            const int* p = m + (size_t)g2 * 4;
            bias[g2] = (p[0] | p[1] | p[2] | p[3]) ? 0.0f : -1442695.0f;
        }
    } else {
        // weight transpose: W [K=256][N=256] fp32 -> WT[p*256+col][k] bf16
        int wb = blk;                    // 0..79
        int y = wb >> 4, bx = wb & 15;
        const float* W; unsigned short* WT; int pidx;
        if (y < 2) { W = (y == 0) ? Wk_p : Wv_p; WT = WTbig; pidx = y; }
        else {
            int q = y - 2;
            W = (q == 0) ? Wq_d : (q == 1 ? Wk_d : Wv_d);
            WT = WTsml; pidx = q;
        }
        int kt = bx >> 2, ct = bx & 3;
        int k0 = kt * 64, c0 = ct * 64;
#pragma unroll
        for (int j = 0; j < 4; j++) {
            int idx = j * 256 + t;
            int kr = idx >> 4, cf = idx & 15;
            float4 v = *(const float4*)&W[(size_t)(k0 + kr) * 256 + c0 + cf * 4];
            sT[(cf * 4 + 0) * 65 + kr] = f2bf(v.x);
            sT[(cf * 4 + 1) * 65 + kr] = f2bf(v.y);
            sT[(cf * 4 + 2) * 65 + kr] = f2bf(v.z);
            sT[(cf * 4 + 3) * 65 + kr] = f2bf(v.w);
        }
        __syncthreads();
#pragma unroll
        for (int j = 0; j < 8; j++) {
            int idx = j * 256 + t;
            int cw = idx >> 5, kq = idx & 31;
            unsigned lo = sT[cw * 65 + kq * 2];
            unsigned hi = sT[cw * 65 + kq * 2 + 1];
            ((unsigned*)WT)[((size_t)pidx * 256 + c0 + cw) * 128 + (k0 >> 1) + kq] =
                lo | (hi << 16);
        }
    }
}

// ---------------------------------------------------------------------------
// Unified bf16 MFMA GEMM (both parts, one launch), XCD-swizzled block ids.
// K/Q tiles: direct head-major bf16 store.
// V tiles: fused transpose epilogue -> writes Vt[(nb*8+h)*32+d][Gk] directly
// with the per-32-key column permutation pos32 = 2*(k&15) + (k>>4).
__global__ __launch_bounds__(256) void gemm_bf16(
        const unsigned short* __restrict__ Abig,
        const unsigned short* __restrict__ WTbig,
        const unsigned short* __restrict__ Asml,
        const unsigned short* __restrict__ WTsml,
        unsigned short* __restrict__ Kp, unsigned short* __restrict__ Vpt,
        unsigned short* __restrict__ Qd, unsigned short* __restrict__ Ksd,
        unsigned short* __restrict__ Vsdt) {
    __shared__ alignas(16) unsigned short lds[128 * 128];   // 32 KB
    unsigned short* As = lds;           // [128][64] k-slab of A
    unsigned short* Bs = lds + 8192;    // [128][64] k-slab of B

    // bijective XCD swizzle: 1408 % 8 == 0 -> 176 consecutive tiles per XCD
    int bid = blockIdx.x;
    int id = (bid & 7) * 176 + (bid >> 3);

    const unsigned short *A, *WT;
    unsigned short *oK0, *oK1, *oV;
    int Gg, lgG, row0, col0;
    float scale0;
    bool isV;
    if (id < 1024) {
        A = Abig; WT = WTbig; oK0 = Kp; oK1 = Kp; oV = Vpt;
        Gg = GP; lgG = 10; scale0 = 1.0f;
        col0 = (id & 3) << 7; row0 = (id >> 2) << 7;
        isV = (col0 >= 256);
    } else {
        int tq = id - 1024;
        A = Asml; WT = WTsml; oK0 = Qd; oK1 = Ksd; oV = Vsdt;
        Gg = GS; lgG = 8; scale0 = LOG2E;
        col0 = (tq % 6) << 7; row0 = (tq / 6) << 7;
        isV = (col0 >= 512);
    }
    const int tid = threadIdx.x;
    const int ln = tid & 63, wave = tid >> 6;
    const int m16 = ln & 15, quad = ln >> 4;
    const int wm = (wave & 1) * 64, wn = (wave >> 1) * 64;

    // staging lane constants: slab j covers units (j*4+wave)*64 + ln
    const uint4* gA[4];
    const uint4* gB[4];
    unsigned ldsoff[4];
#pragma unroll
    for (int j = 0; j < 4; j++) {
        int u = (j * 4 + wave) * 64 + ln;
        int r = u >> 3, s = u & 7;
        int sg = (s - r) & 7;
        gA[j] = (const uint4*)A + (size_t)(row0 + r) * 32 + sg;
        gB[j] = (const uint4*)WT + (size_t)(col0 + r) * 32 + sg;
        ldsoff[j] = (unsigned)((j * 4 + wave) * 512);   // shorts
    }
    // frag read byte-addresses (k0-invariant; kh toggles bit 6)
    int aaddr[4], baddr[4];
#pragma unroll
    for (int i = 0; i < 4; i++) {
        int rA = wm + i * 16 + m16;
        aaddr[i] = rA * 128 + ((quad + rA) & 7) * 16;
        int rB = wn + i * 16 + m16;
        baddr[i] = rB * 128 + ((quad + rB) & 7) * 16;
    }

    floatx4 acc[4][4] = {};
    for (int ko = 0; ko < 32; ko += 8) {     // k in uint4 units (256/8)
        __syncthreads();
#pragma unroll
        for (int j = 0; j < 4; j++) {
            __builtin_amdgcn_global_load_lds(
                (const __attribute__((address_space(1))) void*)(gA[j] + ko),
                (__attribute__((address_space(3))) void*)&As[ldsoff[j]], 16, 0, 0);
            __builtin_amdgcn_global_load_lds(
                (const __attribute__((address_space(1))) void*)(gB[j] + ko),
                (__attribute__((address_space(3))) void*)&Bs[ldsoff[j]], 16, 0, 0);
        }
        __syncthreads();
#pragma unroll
        for (int kh = 0; kh < 2; kh++) {
            short8 af[4], bfr[4];
#pragma unroll
            for (int i = 0; i < 4; i++) {
                af[i]  = *(const short8*)((const char*)As + (aaddr[i] ^ (kh << 6)));
                bfr[i] = *(const short8*)((const char*)Bs + (baddr[i] ^ (kh << 6)));
            }
#pragma unroll
            for (int im = 0; im < 4; im++)
#pragma unroll
                for (int in = 0; in < 4; in++)
                    acc[im][in] = __builtin_amdgcn_mfma_f32_16x16x32_bf16(
                        af[im], bfr[in], acc[im][in], 0, 0, 0);
        }
    }

    if (!isV) {
        // direct epilogue: C layout col=lane&15, row=quad*4+reg
#pragma unroll
        for (int im = 0; im < 4; im++) {
#pragma unroll
            for (int in = 0; in < 4; in++) {
                int colg = col0 + wn + in * 16 + m16;
                int p = colg >> 8, h = (colg >> 5) & 7, d = colg & 31;
                unsigned short* ob = (p == 0) ? oK0 : oK1;
                float sc = (p == 0) ? scale0 : 1.0f;
#pragma unroll
                for (int r = 0; r < 4; r++) {
                    int Mrow = row0 + wm + im * 16 + quad * 4 + r;
                    int nb = Mrow >> lgG, g = Mrow & (Gg - 1);
                    ob[(((size_t)nb * 8 + h) * Gg + g) * 32 + d] =
                        f2bf(acc[im][in][r] * sc);
                }
            }
        }
    } else {
        // fused V-transpose epilogue.
        // key k = wm + im*16 + quad*4 + r (local row, 0..127);
        // permpos(k) = (k>>5)*32 + 8*quad + 2*r + (im&1)
        // LDS tile T[col][pos], XOR-swizzled in the 8-short-group bits.
        __syncthreads();   // all waves done reading As/Bs frags
#pragma unroll
        for (int in = 0; in < 4; in++) {
            int col = wn + in * 16 + m16;                 // 0..127
            unsigned cb = (unsigned)col * 128;
            unsigned swz = (unsigned)((col & 15) << 3);
#pragma unroll
            for (int imp = 0; imp < 2; imp++) {
#pragma unroll
                for (int r = 0; r < 4; r++) {
                    unsigned pos = (unsigned)(wm + imp * 32 + 8 * quad + 2 * r);
                    *(unsigned*)&lds[cb + (pos ^ swz)] =
                        pack_bf16_rne(acc[2 * imp][in][r], acc[2 * imp + 1][in][r]);
                }
            }
        }
        __syncthreads();
        int nb = row0 >> lgG;
        int kbase = row0 & (Gg - 1);
        const int tcol = tid >> 4, p8 = tid & 15;
#pragma unroll
        for (int j = 0; j < 8; j++) {
            int col = j * 16 + tcol;
            int colg = col0 + col;
            int h = (colg >> 5) & 7, d = colg & 31;
            uint4 v = *(const uint4*)&lds[col * 128 + ((p8 * 8) ^ ((col & 15) << 3))];
            *(uint4*)(oV + (((size_t)nb * 8 + h) * 32 + d) * Gg + kbase + p8 * 8) = v;
        }
    }
}

// ---------------------------------------------------------------------------
// Barrier-free flash attention, 32 queries/wave (two 16-q tiles sharing K/V
// frags) + register double-buffered prefetch of next chunk's frags+biases.
// One block = one (n,h): 8 waves cover all 256 queries, so K/V stream is
// read ONCE per head (was twice), and the 8 waves share L1/L2 lines.
struct KVFrag { uint4 k0, k1, v0, v1; float b0, b1; };

__device__ __forceinline__ KVFrag load_frag(
        const uint4* K4, const uint4* V4, const float* bias,
        int c, int Gk8, int m16, int quad) {
    KVFrag f;
    f.k0 = K4[(c * 32 + m16) * 4 + quad];
    f.k1 = K4[(c * 32 + 16 + m16) * 4 + quad];
    f.v0 = V4[(size_t)m16 * Gk8 + c * 4 + quad];
    f.v1 = V4[(size_t)(16 + m16) * Gk8 + c * 4 + quad];
    f.b0 = bias[c * 32 + m16];
    f.b1 = bias[c * 32 + 16 + m16];
    return f;
}

__device__ __forceinline__ void attn_stream(
        const unsigned short* __restrict__ Kb,
        const unsigned short* __restrict__ Vtb,
        const float* __restrict__ bias, int Lk,
        short8 qfA, short8 qfB, unsigned* sPw,
        int m16, int quad, float* lA, float* lB,
        floatx4& oA0, floatx4& oA1, floatx4& oB0, floatx4& oB1) {
    const uint4* K4 = (const uint4*)Kb;
    const uint4* V4 = (const uint4*)Vtb;
    const int Gk8 = Lk >> 3;
    const int nchunks = Lk >> 5;
    KVFrag cur = load_frag(K4, V4, bias, 0, Gk8, m16, quad);
    for (int c = 0; c < nchunks; c++) {
        int cn = (c + 1 < nchunks) ? c + 1 : c;
        KVFrag nxt = load_frag(K4, V4, bias, cn, Gk8, m16, quad);
        union { uint4 u; short8 v; } t0, t1, pA, pB;
        t0.u = cur.k0; t1.u = cur.k1;
        floatx4 z = {0.f, 0.f, 0.f, 0.f};
        __builtin_amdgcn_s_setprio(1);
        floatx4 sA0 = __builtin_amdgcn_mfma_f32_16x16x32_bf16(qfA, t0.v, z, 0, 0, 0);
        floatx4 sA1 = __builtin_amdgcn_mfma_f32_16x16x32_bf16(qfA, t1.v, z, 0, 0, 0);
        floatx4 sB0 = __builtin_amdgcn_mfma_f32_16x16x32_bf16(qfB, t0.v, z, 0, 0, 0);
        floatx4 sB1 = __builtin_amdgcn_mfma_f32_16x16x32_bf16(qfB, t1.v, z, 0, 0, 0);
        __builtin_amdgcn_s_setprio(0);
#pragma unroll
        for (int r = 0; r < 4; r++) {            // row q = quad*4 + r
            float eA0 = EXP2(sA0[r] + cur.b0);
            float eA1 = EXP2(sA1[r] + cur.b1);
            float eB0 = EXP2(sB0[r] + cur.b0);
            float eB1 = EXP2(sB1[r] + cur.b1);
            lA[r] += eA0 + eA1;
            lB[r] += eB0 + eB1;
            sPw[(quad * 4 + r) * 20 + m16] = pack_bf16(eA0, eA1);
            sPw[320 + (quad * 4 + r) * 20 + m16] = pack_bf16(eB0, eB1);
        }
        pA.u = *(const uint4*)&sPw[m16 * 20 + quad * 4];
        pB.u = *(const uint4*)&sPw[320 + m16 * 20 + quad * 4];
        t0.u = cur.v0; t1.u = cur.v1;
        __builtin_amdgcn_s_setprio(1);
        oA0 = __builtin_amdgcn_mfma_f32_16x16x32_bf16(pA.v, t0.v, oA0, 0, 0, 0);
        oA1 = __builtin_amdgcn_mfma_f32_16x16x32_bf16(pA.v, t1.v, oA1, 0, 0, 0);
        oB0 = __builtin_amdgcn_mfma_f32_16x16x32_bf16(pB.v, t0.v, oB0, 0, 0, 0);
        oB1 = __builtin_amdgcn_mfma_f32_16x16x32_bf16(pB.v, t1.v, oB1, 0, 0, 0);
        __builtin_amdgcn_s_setprio(0);
        cur = nxt;
    }
}

__global__ __launch_bounds__(512) void attn_mfma(
        const unsigned short* __restrict__ Qd, const unsigned short* __restrict__ Kp,
        const unsigned short* __restrict__ Vpt, const unsigned short* __restrict__ Ksd,
        const unsigned short* __restrict__ Vsdt, const float* __restrict__ bias_p,
        const float* __restrict__ bias_s, float* __restrict__ out) {
    __shared__ alignas(16) unsigned sP[8][640];
    const int b = blockIdx.x;                // one (n,h) per block
    const int n = b >> 3, h = b & 7;
    const int tid = threadIdx.x, wave = tid >> 6, ln = tid & 63;
    const int m16 = ln & 15, quad = ln >> 4;
    const int q0 = wave * 32;                // tile A: q0.., tile B: q0+16..
    unsigned* sPw = sP[wave];

    union { uint4 u; short8 v; } qfA, qfB;
    qfA.u = ((const uint4*)Qd)[(((size_t)n * 8 + h) * GS + q0 + m16) * 4 + quad];
    qfB.u = ((const uint4*)Qd)[(((size_t)n * 8 + h) * GS + q0 + 16 + m16) * 4 + quad];

    float lAdp[4] = {0, 0, 0, 0}, lBdp[4] = {0, 0, 0, 0};
    float lAdd[4] = {0, 0, 0, 0}, lBdd[4] = {0, 0, 0, 0};
    floatx4 oAdp0 = {}, oAdp1 = {}, oBdp0 = {}, oBdp1 = {};
    floatx4 oAdd0 = {}, oAdd1 = {}, oBdd0 = {}, oBdd1 = {};

    attn_stream(Kp + ((size_t)n * 8 + h) * GP * 32,
                Vpt + ((size_t)n * 8 + h) * GP * 32,
                bias_p + (size_t)n * GP, GP, qfA.v, qfB.v, sPw, m16, quad,
                lAdp, lBdp, oAdp0, oAdp1, oBdp0, oBdp1);
    attn_stream(Ksd + ((size_t)n * 8 + h) * GS * 32,
                Vsdt + ((size_t)n * 8 + h) * GS * 32,
                bias_s + (size_t)n * GS, GS, qfA.v, qfB.v, sPw, m16, quad,
                lAdd, lBdd, oAdd0, oAdd1, oBdd0, oBdd1);

#pragma unroll
    for (int r = 0; r < 4; r++) {
#pragma unroll
        for (int off = 1; off < 16; off <<= 1) {
            lAdp[r] += __shfl_xor(lAdp[r], off, 64);
            lBdp[r] += __shfl_xor(lBdp[r], off, 64);
            lAdd[r] += __shfl_xor(lAdd[r], off, 64);
            lBdd[r] += __shfl_xor(lBdd[r], off, 64);
        }
    }
#pragma unroll
    for (int r = 0; r < 4; r++) {
        // tile A
        int qrowA = q0 + quad * 4 + r;
        bool rmA = (bias_s[(size_t)n * GS + qrowA] == 0.0f);
        float idpA = 1.f / lAdp[r], iddA = 1.f / lAdd[r];
        float* obA = out + ((size_t)n * GS + qrowA) * 256 + h * 32;
        obA[m16]      = rmA ? 0.5f * (oAdp0[r] * idpA + oAdd0[r] * iddA) : 0.f;
        obA[16 + m16] = rmA ? 0.5f * (oAdp1[r] * idpA + oAdd1[r] * iddA) : 0.f;
        // tile B
        int qrowB = q0 + 16 + quad * 4 + r;
        bool rmB = (bias_s[(size_t)n * GS + qrowB] == 0.0f);
        float idpB = 1.f / lBdp[r], iddB = 1.f / lBdd[r];
        float* obB = out + ((size_t)n * GS + qrowB) * 256 + h * 32;
        obB[m16]      = rmB ? 0.5f * (oBdp0[r] * idpB + oBdd0[r] * iddB) : 0.f;
        obB[16 + m16] = rmB ? 0.5f * (oBdp1[r] * idpB + oBdd1[r] * iddB) : 0.f;
    }
}

// ---------------------------------------------------------------------------
extern "C" void kernel_launch(void* const* d_in, const int* in_sizes, int n_in,
                              void* d_out, int out_size, void* d_ws,
                              size_t ws_size, hipStream_t stream) {
    const float* protein   = (const float*)d_in[0];
    const float* smx       = (const float*)d_in[1];
    const int*   mask_prot = (const int*)d_in[2];
    const int*   mask_sm   = (const int*)d_in[3];
    const float* Wk_p = (const float*)d_in[4];
    const float* Wv_p = (const float*)d_in[5];
    const float* Wq_d = (const float*)d_in[6];
    const float* Wk_d = (const float*)d_in[7];
    const float* Wv_d = (const float*)d_in[8];
    float* out = (float*)d_out;

    char* ws = (char*)d_ws;
    unsigned short* prot_g = (unsigned short*)ws; ws += (size_t)N_B * GP * 256 * 2;
    unsigned short* sm_g   = (unsigned short*)ws; ws += (size_t)N_B * GS * 256 * 2;
    unsigned short* WTbig  = (unsigned short*)ws; ws += (size_t)512 * 256 * 2;
    unsigned short* WTsml  = (unsigned short*)ws; ws += (size_t)768 * 256 * 2;
    unsigned short* Kp     = (unsigned short*)ws; ws += (size_t)N_B * H_N * GP * 32 * 2;
    unsigned short* Vpt    = (unsigned short*)ws; ws += (size_t)N_B * H_N * GP * 32 * 2;
    unsigned short* Qd     = (unsigned short*)ws; ws += (size_t)N_B * H_N * GS * 32 * 2;
    unsigned short* Ksd    = (unsigned short*)ws; ws += (size_t)N_B * H_N * GS * 32 * 2;
    unsigned short* Vsdt   = (unsigned short*)ws; ws += (size_t)N_B * H_N * GS * 32 * 2;
    float* bias_p = (float*)ws; ws += (size_t)N_B * GP * 4;
    float* bias_s = (float*)ws; ws += (size_t)N_B * GS * 4;

    // 1. fused prologue: weight transposes (front) + group means + biases
    prologue_w<<<PRO_BLOCKS + WT_BLOCKS, 256, 0, stream>>>(
        (const float4*)protein, (const float4*)smx, mask_prot, mask_sm,
        (ushort4*)prot_g, (ushort4*)sm_g, bias_p, bias_s,
        Wk_p, Wv_p, Wq_d, Wk_d, Wv_d, WTbig, WTsml);

    // 2. unified MFMA projections -> head-major bf16 (Q pre-scaled by log2e),
    //    V written directly in transposed+permuted attention layout
    gemm_bf16<<<1024 + 384, 256, 0, stream>>>(
        prot_g, WTbig, sm_g, WTsml, Kp, Vpt, Qd, Ksd, Vsdt);

    // 3. barrier-free dual-stream flash-MFMA attention + merge
    //    (one block per (n,h): K/V streamed once, 8 waves share the stream)
    attn_mfma<<<N_B * H_N, 512, 0, stream>>>(Qd, Kp, Vpt, Ksd, Vsdt,
                                             bias_p, bias_s, out);
}

// Round 8
// 276.457 us; speedup vs baseline: 1.0515x; 1.0052x over previous
//
#include <hip/hip_runtime.h>
#include <cstdint>
#include <cstddef>

// Problem constants (fixed by setup_inputs)
#define N_B 32
#define D_MODEL 256
#define H_N 8
#define HD 32
#define GP 1024   // grouped protein length
#define GS 256    // grouped sm length
#define LOG2E 1.4426950408889634f

typedef __attribute__((ext_vector_type(8))) _Float16 half8;   // 8 fp16 = 4 VGPRs
typedef __attribute__((ext_vector_type(4))) float floatx4;

#if __has_builtin(__builtin_amdgcn_exp2f)
#define EXP2(x) __builtin_amdgcn_exp2f(x)
#else
#define EXP2(x) exp2f(x)
#endif

// fp32 -> fp16 bits, RNE (single v_cvt_f16_f32)
__device__ __forceinline__ unsigned short f2h(float f) {
    _Float16 h = (_Float16)f;
    return __builtin_bit_cast(unsigned short, h);
}

// exact-RNE pack of two fp16 into one dword (lo = a, hi = b)
__device__ __forceinline__ unsigned pack_h_rne(float a, float b) {
    return (unsigned)f2h(a) | ((unsigned)f2h(b) << 16);
}

// ---------------------------------------------------------------------------
// Fused prologue: (head blocks) all 5 weight transposes, then both
// group-means (fp32 -> fp16) + both mask biases.
#define PRO_A (N_B * GP * 64)
#define PRO_B (N_B * GS * 64)
#define PRO_C (N_B * GP)
#define PRO_D (N_B * GS)
#define PRO_BLOCKS ((PRO_A + PRO_B + PRO_C + PRO_D) / 256)   // 10400
#define WT_BLOCKS 80
__global__ __launch_bounds__(256) void prologue_w(
        const float4* __restrict__ prot, const float4* __restrict__ smx,
        const int* __restrict__ mp, const int* __restrict__ ms,
        ushort4* __restrict__ prot_g, ushort4* __restrict__ sm_g,
        float* __restrict__ bias_p, float* __restrict__ bias_s,
        const float* __restrict__ Wk_p, const float* __restrict__ Wv_p,
        const float* __restrict__ Wq_d, const float* __restrict__ Wk_d,
        const float* __restrict__ Wv_d,
        unsigned short* __restrict__ WTbig, unsigned short* __restrict__ WTsml) {
    __shared__ unsigned short sT[64 * 65];
    int blk = blockIdx.x;
    int t = threadIdx.x;
    if (blk >= WT_BLOCKS) {
        int gid = (blk - WT_BLOCKS) * 256 + t;
        if (gid < PRO_A + PRO_B) {
            const float4* x; ushort4* xg; int g2;
            if (gid < PRO_A) { x = prot; xg = prot_g; g2 = gid; }
            else { x = smx; xg = sm_g; g2 = gid - PRO_A; }
            int row = g2 >> 6, c = g2 & 63;
            const float4* p = x + (size_t)row * 256 + c;
            float4 a = p[0], b = p[64], cc = p[128], d = p[192];
            ushort4 r;
            r.x = f2h(0.25f * (a.x + b.x + cc.x + d.x));
            r.y = f2h(0.25f * (a.y + b.y + cc.y + d.y));
            r.z = f2h(0.25f * (a.z + b.z + cc.z + d.z));
            r.w = f2h(0.25f * (a.w + b.w + cc.w + d.w));
            xg[g2] = r;
        } else {
            int g2 = gid - (PRO_A + PRO_B);
            const int* m; float* bias;
            if (g2 < PRO_C) { m = mp; bias = bias_p; }
            else { m = ms; bias = bias_s; g2 -= PRO_C; }
            const int* p = m + (size_t)g2 * 4;
            bias[g2] = (p[0] | p[1] | p[2] | p[3]) ? 0.0f : -1442695.0f;
        }
    } else {
        // weight transpose: W [K=256][N=256] fp32 -> WT[p*256+col][k] fp16
        int wb = blk;                    // 0..79
        int y = wb >> 4, bx = wb & 15;
        const float* W; unsigned short* WT; int pidx;
        if (y < 2) { W = (y == 0) ? Wk_p : Wv_p; WT = WTbig; pidx = y; }
        else {
            int q = y - 2;
            W = (q == 0) ? Wq_d : (q == 1 ? Wk_d : Wv_d);
            WT = WTsml; pidx = q;
        }
        int kt = bx >> 2, ct = bx & 3;
        int k0 = kt * 64, c0 = ct * 64;
#pragma unroll
        for (int j = 0; j < 4; j++) {
            int idx = j * 256 + t;
            int kr = idx >> 4, cf = idx & 15;
            float4 v = *(const float4*)&W[(size_t)(k0 + kr) * 256 + c0 + cf * 4];
            sT[(cf * 4 + 0) * 65 + kr] = f2h(v.x);
            sT[(cf * 4 + 1) * 65 + kr] = f2h(v.y);
            sT[(cf * 4 + 2) * 65 + kr] = f2h(v.z);
            sT[(cf * 4 + 3) * 65 + kr] = f2h(v.w);
        }
        __syncthreads();
#pragma unroll
        for (int j = 0; j < 8; j++) {
            int idx = j * 256 + t;
            int cw = idx >> 5, kq = idx & 31;
            unsigned lo = sT[cw * 65 + kq * 2];
            unsigned hi = sT[cw * 65 + kq * 2 + 1];
            ((unsigned*)WT)[((size_t)pidx * 256 + c0 + cw) * 128 + (k0 >> 1) + kq] =
                lo | (hi << 16);
        }
    }
}

// ---------------------------------------------------------------------------
// Unified fp16 MFMA GEMM (both parts, one launch), XCD-swizzled block ids.
// K/Q tiles: direct head-major fp16 store.
// V tiles: fused transpose epilogue -> writes Vt[(nb*8+h)*32+d][Gk] directly
// with the per-32-key column permutation pos32 = 2*(k&15) + (k>>4).
__global__ __launch_bounds__(256) void gemm_f16(
        const unsigned short* __restrict__ Abig,
        const unsigned short* __restrict__ WTbig,
        const unsigned short* __restrict__ Asml,
        const unsigned short* __restrict__ WTsml,
        unsigned short* __restrict__ Kp, unsigned short* __restrict__ Vpt,
        unsigned short* __restrict__ Qd, unsigned short* __restrict__ Ksd,
        unsigned short* __restrict__ Vsdt) {
    __shared__ alignas(16) unsigned short lds[128 * 128];   // 32 KB
    unsigned short* As = lds;           // [128][64] k-slab of A
    unsigned short* Bs = lds + 8192;    // [128][64] k-slab of B

    // bijective XCD swizzle: 1408 % 8 == 0 -> 176 consecutive tiles per XCD
    int bid = blockIdx.x;
    int id = (bid & 7) * 176 + (bid >> 3);

    const unsigned short *A, *WT;
    unsigned short *oK0, *oK1, *oV;
    int Gg, lgG, row0, col0;
    float scale0;
    bool isV;
    if (id < 1024) {
        A = Abig; WT = WTbig; oK0 = Kp; oK1 = Kp; oV = Vpt;
        Gg = GP; lgG = 10; scale0 = 1.0f;
        col0 = (id & 3) << 7; row0 = (id >> 2) << 7;
        isV = (col0 >= 256);
    } else {
        int tq = id - 1024;
        A = Asml; WT = WTsml; oK0 = Qd; oK1 = Ksd; oV = Vsdt;
        Gg = GS; lgG = 8; scale0 = LOG2E;
        col0 = (tq % 6) << 7; row0 = (tq / 6) << 7;
        isV = (col0 >= 512);
    }
    const int tid = threadIdx.x;
    const int ln = tid & 63, wave = tid >> 6;
    const int m16 = ln & 15, quad = ln >> 4;
    const int wm = (wave & 1) * 64, wn = (wave >> 1) * 64;

    // staging lane constants: slab j covers units (j*4+wave)*64 + ln
    const uint4* gA[4];
    const uint4* gB[4];
    unsigned ldsoff[4];
#pragma unroll
    for (int j = 0; j < 4; j++) {
        int u = (j * 4 + wave) * 64 + ln;
        int r = u >> 3, s = u & 7;
        int sg = (s - r) & 7;
        gA[j] = (const uint4*)A + (size_t)(row0 + r) * 32 + sg;
        gB[j] = (const uint4*)WT + (size_t)(col0 + r) * 32 + sg;
        ldsoff[j] = (unsigned)((j * 4 + wave) * 512);   // shorts
    }
    // frag read byte-addresses (k0-invariant; kh toggles bit 6)
    int aaddr[4], baddr[4];
#pragma unroll
    for (int i = 0; i < 4; i++) {
        int rA = wm + i * 16 + m16;
        aaddr[i] = rA * 128 + ((quad + rA) & 7) * 16;
        int rB = wn + i * 16 + m16;
        baddr[i] = rB * 128 + ((quad + rB) & 7) * 16;
    }

    floatx4 acc[4][4] = {};
    for (int ko = 0; ko < 32; ko += 8) {     // k in uint4 units (256/8)
        __syncthreads();
#pragma unroll
        for (int j = 0; j < 4; j++) {
            __builtin_amdgcn_global_load_lds(
                (const __attribute__((address_space(1))) void*)(gA[j] + ko),
                (__attribute__((address_space(3))) void*)&As[ldsoff[j]], 16, 0, 0);
            __builtin_amdgcn_global_load_lds(
                (const __attribute__((address_space(1))) void*)(gB[j] + ko),
                (__attribute__((address_space(3))) void*)&Bs[ldsoff[j]], 16, 0, 0);
        }
        __syncthreads();
#pragma unroll
        for (int kh = 0; kh < 2; kh++) {
            half8 af[4], bfr[4];
#pragma unroll
            for (int i = 0; i < 4; i++) {
                af[i]  = *(const half8*)((const char*)As + (aaddr[i] ^ (kh << 6)));
                bfr[i] = *(const half8*)((const char*)Bs + (baddr[i] ^ (kh << 6)));
            }
#pragma unroll
            for (int im = 0; im < 4; im++)
#pragma unroll
                for (int in = 0; in < 4; in++)
                    acc[im][in] = __builtin_amdgcn_mfma_f32_16x16x32_f16(
                        af[im], bfr[in], acc[im][in], 0, 0, 0);
        }
    }

    if (!isV) {
        // direct epilogue: C layout col=lane&15, row=quad*4+reg
#pragma unroll
        for (int im = 0; im < 4; im++) {
#pragma unroll
            for (int in = 0; in < 4; in++) {
                int colg = col0 + wn + in * 16 + m16;
                int p = colg >> 8, h = (colg >> 5) & 7, d = colg & 31;
                unsigned short* ob = (p == 0) ? oK0 : oK1;
                float sc = (p == 0) ? scale0 : 1.0f;
#pragma unroll
                for (int r = 0; r < 4; r++) {
                    int Mrow = row0 + wm + im * 16 + quad * 4 + r;
                    int nb = Mrow >> lgG, g = Mrow & (Gg - 1);
                    ob[(((size_t)nb * 8 + h) * Gg + g) * 32 + d] =
                        f2h(acc[im][in][r] * sc);
                }
            }
        }
    } else {
        // fused V-transpose epilogue.
        // key k = wm + im*16 + quad*4 + r (local row, 0..127);
        // permpos(k) = (k>>5)*32 + 8*quad + 2*r + (im&1)
        // LDS tile T[col][pos], XOR-swizzled in the 8-short-group bits.
        __syncthreads();   // all waves done reading As/Bs frags
#pragma unroll
        for (int in = 0; in < 4; in++) {
            int col = wn + in * 16 + m16;                 // 0..127
            unsigned cb = (unsigned)col * 128;
            unsigned swz = (unsigned)((col & 15) << 3);
#pragma unroll
            for (int imp = 0; imp < 2; imp++) {
#pragma unroll
                for (int r = 0; r < 4; r++) {
                    unsigned pos = (unsigned)(wm + imp * 32 + 8 * quad + 2 * r);
                    *(unsigned*)&lds[cb + (pos ^ swz)] =
                        pack_h_rne(acc[2 * imp][in][r], acc[2 * imp + 1][in][r]);
                }
            }
        }
        __syncthreads();
        int nb = row0 >> lgG;
        int kbase = row0 & (Gg - 1);
        const int tcol = tid >> 4, p8 = tid & 15;
#pragma unroll
        for (int j = 0; j < 8; j++) {
            int col = j * 16 + tcol;
            int colg = col0 + col;
            int h = (colg >> 5) & 7, d = colg & 31;
            uint4 v = *(const uint4*)&lds[col * 128 + ((p8 * 8) ^ ((col & 15) << 3))];
            *(uint4*)(oV + (((size_t)nb * 8 + h) * 32 + d) * Gg + kbase + p8 * 8) = v;
        }
    }
}

// ---------------------------------------------------------------------------
// Barrier-free flash attention, 32 queries/wave (two 16-q tiles sharing K/V
// frags) + register double-buffered prefetch of next chunk's frags+biases.
// One block = one (n,h): 8 waves cover all 256 queries, K/V streamed once.
// NUMERICS: fp16 pipeline; softmax denominator l accumulates the SAME
// fp16-rounded (RNE) P values the PV MFMA consumes, so rounding cancels in
// the ratio.  P is range-safe in fp16 (P <= ~4e3 << 65504).
struct KVFrag { uint4 k0, k1, v0, v1; float b0, b1; };

__device__ __forceinline__ KVFrag load_frag(
        const uint4* K4, const uint4* V4, const float* bias,
        int c, int Gk8, int m16, int quad) {
    KVFrag f;
    f.k0 = K4[(c * 32 + m16) * 4 + quad];
    f.k1 = K4[(c * 32 + 16 + m16) * 4 + quad];
    f.v0 = V4[(size_t)m16 * Gk8 + c * 4 + quad];
    f.v1 = V4[(size_t)(16 + m16) * Gk8 + c * 4 + quad];
    f.b0 = bias[c * 32 + m16];
    f.b1 = bias[c * 32 + 16 + m16];
    return f;
}

__device__ __forceinline__ void attn_stream(
        const unsigned short* __restrict__ Kb,
        const unsigned short* __restrict__ Vtb,
        const float* __restrict__ bias, int Lk,
        half8 qfA, half8 qfB, unsigned* sPw,
        int m16, int quad, float* lA, float* lB,
        floatx4& oA0, floatx4& oA1, floatx4& oB0, floatx4& oB1) {
    const uint4* K4 = (const uint4*)Kb;
    const uint4* V4 = (const uint4*)Vtb;
    const int Gk8 = Lk >> 3;
    const int nchunks = Lk >> 5;
    KVFrag cur = load_frag(K4, V4, bias, 0, Gk8, m16, quad);
    for (int c = 0; c < nchunks; c++) {
        int cn = (c + 1 < nchunks) ? c + 1 : c;
        KVFrag nxt = load_frag(K4, V4, bias, cn, Gk8, m16, quad);
        union { uint4 u; half8 v; } t0, t1, pA, pB;
        t0.u = cur.k0; t1.u = cur.k1;
        floatx4 z = {0.f, 0.f, 0.f, 0.f};
        __builtin_amdgcn_s_setprio(1);
        floatx4 sA0 = __builtin_amdgcn_mfma_f32_16x16x32_f16(qfA, t0.v, z, 0, 0, 0);
        floatx4 sA1 = __builtin_amdgcn_mfma_f32_16x16x32_f16(qfA, t1.v, z, 0, 0, 0);
        floatx4 sB0 = __builtin_amdgcn_mfma_f32_16x16x32_f16(qfB, t0.v, z, 0, 0, 0);
        floatx4 sB1 = __builtin_amdgcn_mfma_f32_16x16x32_f16(qfB, t1.v, z, 0, 0, 0);
        __builtin_amdgcn_s_setprio(0);
#pragma unroll
        for (int r = 0; r < 4; r++) {            // row q = quad*4 + r
            // RNE fp16 round each exponential; l uses the SAME rounded values
            _Float16 hA0 = (_Float16)EXP2(sA0[r] + cur.b0);
            _Float16 hA1 = (_Float16)EXP2(sA1[r] + cur.b1);
            _Float16 hB0 = (_Float16)EXP2(sB0[r] + cur.b0);
            _Float16 hB1 = (_Float16)EXP2(sB1[r] + cur.b1);
            lA[r] += (float)hA0 + (float)hA1;
            lB[r] += (float)hB0 + (float)hB1;
            unsigned uA = (unsigned)__builtin_bit_cast(unsigned short, hA0) |
                          ((unsigned)__builtin_bit_cast(unsigned short, hA1) << 16);
            unsigned uB = (unsigned)__builtin_bit_cast(unsigned short, hB0) |
                          ((unsigned)__builtin_bit_cast(unsigned short, hB1) << 16);
            sPw[(quad * 4 + r) * 20 + m16] = uA;
            sPw[320 + (quad * 4 + r) * 20 + m16] = uB;
        }
        pA.u = *(const uint4*)&sPw[m16 * 20 + quad * 4];
        pB.u = *(const uint4*)&sPw[320 + m16 * 20 + quad * 4];
        t0.u = cur.v0; t1.u = cur.v1;
        __builtin_amdgcn_s_setprio(1);
        oA0 = __builtin_amdgcn_mfma_f32_16x16x32_f16(pA.v, t0.v, oA0, 0, 0, 0);
        oA1 = __builtin_amdgcn_mfma_f32_16x16x32_f16(pA.v, t1.v, oA1, 0, 0, 0);
        oB0 = __builtin_amdgcn_mfma_f32_16x16x32_f16(pB.v, t0.v, oB0, 0, 0, 0);
        oB1 = __builtin_amdgcn_mfma_f32_16x16x32_f16(pB.v, t1.v, oB1, 0, 0, 0);
        __builtin_amdgcn_s_setprio(0);
        cur = nxt;
    }
}

__global__ __launch_bounds__(512) void attn_mfma(
        const unsigned short* __restrict__ Qd, const unsigned short* __restrict__ Kp,
        const unsigned short* __restrict__ Vpt, const unsigned short* __restrict__ Ksd,
        const unsigned short* __restrict__ Vsdt, const float* __restrict__ bias_p,
        const float* __restrict__ bias_s, float* __restrict__ out) {
    __shared__ alignas(16) unsigned sP[8][640];
    const int b = blockIdx.x;                // one (n,h) per block
    const int n = b >> 3, h = b & 7;
    const int tid = threadIdx.x, wave = tid >> 6, ln = tid & 63;
    const int m16 = ln & 15, quad = ln >> 4;
    const int q0 = wave * 32;                // tile A: q0.., tile B: q0+16..
    unsigned* sPw = sP[wave];

    union { uint4 u; half8 v; } qfA, qfB;
    qfA.u = ((const uint4*)Qd)[(((size_t)n * 8 + h) * GS + q0 + m16) * 4 + quad];
    qfB.u = ((const uint4*)Qd)[(((size_t)n * 8 + h) * GS + q0 + 16 + m16) * 4 + quad];

    float lAdp[4] = {0, 0, 0, 0}, lBdp[4] = {0, 0, 0, 0};
    float lAdd[4] = {0, 0, 0, 0}, lBdd[4] = {0, 0, 0, 0};
    floatx4 oAdp0 = {}, oAdp1 = {}, oBdp0 = {}, oBdp1 = {};
    floatx4 oAdd0 = {}, oAdd1 = {}, oBdd0 = {}, oBdd1 = {};

    attn_stream(Kp + ((size_t)n * 8 + h) * GP * 32,
                Vpt + ((size_t)n * 8 + h) * GP * 32,
                bias_p + (size_t)n * GP, GP, qfA.v, qfB.v, sPw, m16, quad,
                lAdp, lBdp, oAdp0, oAdp1, oBdp0, oBdp1);
    attn_stream(Ksd + ((size_t)n * 8 + h) * GS * 32,
                Vsdt + ((size_t)n * 8 + h) * GS * 32,
                bias_s + (size_t)n * GS, GS, qfA.v, qfB.v, sPw, m16, quad,
                lAdd, lBdd, oAdd0, oAdd1, oBdd0, oBdd1);

#pragma unroll
    for (int r = 0; r < 4; r++) {
#pragma unroll
        for (int off = 1; off < 16; off <<= 1) {
            lAdp[r] += __shfl_xor(lAdp[r], off, 64);
            lBdp[r] += __shfl_xor(lBdp[r], off, 64);
            lAdd[r] += __shfl_xor(lAdd[r], off, 64);
            lBdd[r] += __shfl_xor(lBdd[r], off, 64);
        }
    }
#pragma unroll
    for (int r = 0; r < 4; r++) {
        // tile A
        int qrowA = q0 + quad * 4 + r;
        bool rmA = (bias_s[(size_t)n * GS + qrowA] == 0.0f);
        float idpA = 1.f / lAdp[r], iddA = 1.f / lAdd[r];
        float* obA = out + ((size_t)n * GS + qrowA) * 256 + h * 32;
        obA[m16]      = rmA ? 0.5f * (oAdp0[r] * idpA + oAdd0[r] * iddA) : 0.f;
        obA[16 + m16] = rmA ? 0.5f * (oAdp1[r] * idpA + oAdd1[r] * iddA) : 0.f;
        // tile B
        int qrowB = q0 + 16 + quad * 4 + r;
        bool rmB = (bias_s[(size_t)n * GS + qrowB] == 0.0f);
        float idpB = 1.f / lBdp[r], iddB = 1.f / lBdd[r];
        float* obB = out + ((size_t)n * GS + qrowB) * 256 + h * 32;
        obB[m16]      = rmB ? 0.5f * (oBdp0[r] * idpB + oBdd0[r] * iddB) : 0.f;
        obB[16 + m16] = rmB ? 0.5f * (oBdp1[r] * idpB + oBdd1[r] * iddB) : 0.f;
    }
}

// ---------------------------------------------------------------------------
extern "C" void kernel_launch(void* const* d_in, const int* in_sizes, int n_in,
                              void* d_out, int out_size, void* d_ws,
                              size_t ws_size, hipStream_t stream) {
    const float* protein   = (const float*)d_in[0];
    const float* smx       = (const float*)d_in[1];
    const int*   mask_prot = (const int*)d_in[2];
    const int*   mask_sm   = (const int*)d_in[3];
    const float* Wk_p = (const float*)d_in[4];
    const float* Wv_p = (const float*)d_in[5];
    const float* Wq_d = (const float*)d_in[6];
    const float* Wk_d = (const float*)d_in[7];
    const float* Wv_d = (const float*)d_in[8];
    float* out = (float*)d_out;

    char* ws = (char*)d_ws;
    unsigned short* prot_g = (unsigned short*)ws; ws += (size_t)N_B * GP * 256 * 2;
    unsigned short* sm_g   = (unsigned short*)ws; ws += (size_t)N_B * GS * 256 * 2;
    unsigned short* WTbig  = (unsigned short*)ws; ws += (size_t)512 * 256 * 2;
    unsigned short* WTsml  = (unsigned short*)ws; ws += (size_t)768 * 256 * 2;
    unsigned short* Kp     = (unsigned short*)ws; ws += (size_t)N_B * H_N * GP * 32 * 2;
    unsigned short* Vpt    = (unsigned short*)ws; ws += (size_t)N_B * H_N * GP * 32 * 2;
    unsigned short* Qd     = (unsigned short*)ws; ws += (size_t)N_B * H_N * GS * 32 * 2;
    unsigned short* Ksd    = (unsigned short*)ws; ws += (size_t)N_B * H_N * GS * 32 * 2;
    unsigned short* Vsdt   = (unsigned short*)ws; ws += (size_t)N_B * H_N * GS * 32 * 2;
    float* bias_p = (float*)ws; ws += (size_t)N_B * GP * 4;
    float* bias_s = (float*)ws; ws += (size_t)N_B * GS * 4;

    // 1. fused prologue: weight transposes (front) + group means + biases
    prologue_w<<<PRO_BLOCKS + WT_BLOCKS, 256, 0, stream>>>(
        (const float4*)protein, (const float4*)smx, mask_prot, mask_sm,
        (ushort4*)prot_g, (ushort4*)sm_g, bias_p, bias_s,
        Wk_p, Wv_p, Wq_d, Wk_d, Wv_d, WTbig, WTsml);

    // 2. unified fp16 MFMA projections -> head-major (Q pre-scaled by log2e),
    //    V written directly in transposed+permuted attention layout
    gemm_f16<<<1024 + 384, 256, 0, stream>>>(
        prot_g, WTbig, sm_g, WTsml, Kp, Vpt, Qd, Ksd, Vsdt);

    // 3. barrier-free dual-stream flash-MFMA attention + merge
    attn_mfma<<<N_B * H_N, 512, 0, stream>>>(Qd, Kp, Vpt, Ksd, Vsdt,
                                             bias_p, bias_s, out);
}